// Round 1
// baseline (415.968 us; speedup 1.0000x reference)
//
#include <hip/hip_runtime.h>
#include <cstdint>

#define DEV static __device__ __forceinline__

typedef unsigned short u16;
typedef unsigned int u32;
using short8 = __attribute__((ext_vector_type(8))) short;
using f32x4  = __attribute__((ext_vector_type(4))) float;

constexpr int Bz = 4, Tz = 2048, Dz = 1024, Hz = 16;
// fold 1/sqrt(64) and log2(e) into Q so attention uses exp2 directly
constexpr float QSCALE = 0.125f * 1.4426950408889634f;

DEV u16 f2bf(float x) {
  union { float f; u32 u; } c; c.f = x;
  u32 u = c.u;
  return (u16)((u + 0x7FFFu + ((u >> 16) & 1u)) >> 16);
}

// ---- weight transpose + convert: W (K x N fp32, K=N=1024) -> WT (N x K bf16)
__global__ void wt_kernel(const float* __restrict__ W, u16* __restrict__ WT) {
  __shared__ float tile[32][33];
  int n0 = blockIdx.x * 32, k0 = blockIdx.y * 32;
  int tx = threadIdx.x & 31, ty = threadIdx.x >> 5;
  #pragma unroll
  for (int i = 0; i < 32; i += 8)
    tile[ty + i][tx] = W[(size_t)(k0 + ty + i) * Dz + n0 + tx];
  __syncthreads();
  #pragma unroll
  for (int i = 0; i < 32; i += 8)
    WT[(size_t)(n0 + ty + i) * Dz + k0 + tx] = f2bf(tile[tx][ty + i]);
}

// ---- GEMM: C[M=8192, N=1024] = A[M,1024] @ W[1024,N] (+bias)
// AMODE 0: A fp32 (converted to bf16 during staging); 1: A bf16
// EPI 0: scatter bf16 to (B,H,T,64) with (acc+bias)*scale ; 1: fp32 out + bias
template <int AMODE, int EPI>
__global__ __launch_bounds__(256) void gemm_kernel(
    const void* __restrict__ Aptr, const u16* __restrict__ WT,
    const float* __restrict__ bias, void* __restrict__ Cptr, float scale)
{
  __shared__ char lds[32 * 1024];
  char* Alds = lds;            // [128 rows][64 k] bf16, 128B rows, XOR-swizzled
  char* Blds = lds + 16 * 1024; // [128 n][64 k] bf16 (B^T), XOR-swizzled

  const int tid = threadIdx.x;
  const int lane = tid & 63, wid = tid >> 6;
  const int g = lane >> 4, l15 = lane & 15;
  const int n0 = blockIdx.x * 128, m0 = blockIdx.y * 128;
  const int wm = (wid >> 1) * 64, wn = (wid & 1) * 64;

  f32x4 acc[4][4] = {};

  for (int k0 = 0; k0 < Dz; k0 += 64) {
    if (AMODE == 0) {
      const float* A = (const float*)Aptr;
      #pragma unroll
      for (int i = 0; i < 8; ++i) {
        int c = tid + i * 256;              // 2048 chunks of 4 floats
        int row = c >> 4, f0 = (c & 15) * 4;
        float4 v = *(const float4*)(A + (size_t)(m0 + row) * Dz + k0 + f0);
        u32 lo = (u32)f2bf(v.x) | ((u32)f2bf(v.y) << 16);
        u32 hi = (u32)f2bf(v.z) | ((u32)f2bf(v.w) << 16);
        int off = row * 128 + ((f0 * 2) ^ ((row & 7) << 4));
        *(uint2*)(Alds + off) = make_uint2(lo, hi);
      }
    } else {
      const u16* A = (const u16*)Aptr;
      #pragma unroll
      for (int i = 0; i < 4; ++i) {
        int c = tid + i * 256;              // 1024 chunks of 16B
        int row = c >> 3, cb = (c & 7) * 16;
        uint4 v = *(const uint4*)(A + (size_t)(m0 + row) * Dz + k0 + (cb >> 1));
        *(uint4*)(Alds + row * 128 + (cb ^ ((row & 7) << 4))) = v;
      }
    }
    #pragma unroll
    for (int i = 0; i < 4; ++i) {
      int c = tid + i * 256;
      int row = c >> 3, cb = (c & 7) * 16;
      uint4 v = *(const uint4*)(WT + (size_t)(n0 + row) * Dz + k0 + (cb >> 1));
      *(uint4*)(Blds + row * 128 + (cb ^ ((row & 7) << 4))) = v;
    }
    __syncthreads();

    #pragma unroll
    for (int kc = 0; kc < 2; ++kc) {
      short8 af[4], bfv[4];
      #pragma unroll
      for (int mt = 0; mt < 4; ++mt) {
        int row = wm + mt * 16 + l15;
        af[mt] = *(const short8*)(Alds + row * 128 + ((kc * 64 + g * 16) ^ ((row & 7) << 4)));
      }
      #pragma unroll
      for (int nt = 0; nt < 4; ++nt) {
        int row = wn + nt * 16 + l15;
        bfv[nt] = *(const short8*)(Blds + row * 128 + ((kc * 64 + g * 16) ^ ((row & 7) << 4)));
      }
      #pragma unroll
      for (int mt = 0; mt < 4; ++mt)
        #pragma unroll
        for (int nt = 0; nt < 4; ++nt)
          acc[mt][nt] = __builtin_amdgcn_mfma_f32_16x16x32_bf16(af[mt], bfv[nt], acc[mt][nt], 0, 0, 0);
    }
    __syncthreads();
  }

  if (EPI == 0) {
    u16* C = (u16*)Cptr;
    #pragma unroll
    for (int nt = 0; nt < 4; ++nt) {
      int n = n0 + wn + nt * 16 + l15;
      float bv = bias[n];
      int h = n >> 6, dh = n & 63;
      #pragma unroll
      for (int mt = 0; mt < 4; ++mt)
        #pragma unroll
        for (int r = 0; r < 4; ++r) {
          int m = m0 + wm + mt * 16 + g * 4 + r;
          int bb = m >> 11, t = m & 2047;
          float val = (acc[mt][nt][r] + bv) * scale;
          C[((size_t)(bb * Hz + h) * Tz + t) * 64 + dh] = f2bf(val);
        }
    }
  } else {
    float* C = (float*)Cptr;
    #pragma unroll
    for (int nt = 0; nt < 4; ++nt) {
      int n = n0 + wn + nt * 16 + l15;
      float bv = bias[n];
      #pragma unroll
      for (int mt = 0; mt < 4; ++mt)
        #pragma unroll
        for (int r = 0; r < 4; ++r) {
          int m = m0 + wm + mt * 16 + g * 4 + r;
          C[(size_t)m * Dz + n] = acc[mt][nt][r] + bv;
        }
    }
  }
}

// ---- flash attention: q,k,v in (B,H,T,64) bf16 (q pre-scaled by 0.125*log2e)
// 4 waves x 16 q-rows, KV tiles of 64, causal. Swapped MFMAs:
//   S^T = mfma(K, Q)  -> lane-local q for softmax (col = lane&15 = q)
//   O^T = mfma(V^T, P^T) -> col = q, so m/l rescale needs no shuffles
__global__ __launch_bounds__(256) void attn_kernel(
    const u16* __restrict__ Q, const u16* __restrict__ K,
    const u16* __restrict__ V, u16* __restrict__ CTX)
{
  __shared__ char lds[24 * 1024];
  char* Klds = lds;            // [64 key][64 dk] bf16, swizzled ^((key&7)<<4)
  char* Vlds = lds + 8192;     // V^T [64 dv][64 key] bf16, swizzled ^((dv&7)<<4)
  char* Plds = lds + 16384;    // per-wave 2KB: [16 q][64 key], swizzled ^((q&7)<<4)

  const int tid = threadIdx.x;
  const int lane = tid & 63, wid = tid >> 6;
  const int g = lane >> 4, l15 = lane & 15;
  const int t0 = blockIdx.x * 64;
  const int bh = blockIdx.y;

  const u16* qb = Q + (size_t)bh * Tz * 64;
  const u16* kb = K + (size_t)bh * Tz * 64;
  const u16* vb = V + (size_t)bh * Tz * 64;

  const int wq0 = t0 + wid * 16;

  short8 qf[2];
  #pragma unroll
  for (int kc = 0; kc < 2; ++kc)
    qf[kc] = *(const short8*)(qb + (size_t)(wq0 + l15) * 64 + kc * 32 + g * 8);

  f32x4 ot[4] = {};
  float m_run = -3.0e38f, l_run = 0.f;

  const int ntiles = t0 / 64 + 1;
  for (int kt = 0; kt < ntiles; ++kt) {
    const int kv0 = kt * 64;
    __syncthreads();  // prior-iter LDS reads done before restage
    #pragma unroll
    for (int i = 0; i < 2; ++i) {
      int c = tid + i * 256;           // 512 chunks of 16B
      int key = c >> 3;
      int cb = (c & 7) * 16;
      const u16* src = kb + (size_t)(kv0 + key) * 64 + (cb >> 1);
      *(uint4*)(Klds + key * 128 + (cb ^ ((key & 7) << 4))) = *(const uint4*)src;
      int dv0 = (c & 7) * 8;
      union { uint4 v; u16 s[8]; } vv;
      vv.v = *(const uint4*)(vb + (size_t)(kv0 + key) * 64 + dv0);
      #pragma unroll
      for (int j = 0; j < 8; ++j) {
        int dv = dv0 + j;
        *(u16*)(Vlds + dv * 128 + ((key * 2) ^ ((dv & 7) << 4))) = vv.s[j];
      }
    }
    __syncthreads();

    // S^T tiles: rows = keys (mt*16 + 4g + r), cols = q (= l15)
    f32x4 st[4];
    #pragma unroll
    for (int mt = 0; mt < 4; ++mt) {
      f32x4 a = {0.f, 0.f, 0.f, 0.f};
      #pragma unroll
      for (int kc = 0; kc < 2; ++kc) {
        int row = mt * 16 + l15;
        short8 kf = *(const short8*)(Klds + row * 128 + ((kc * 64 + g * 16) ^ ((row & 7) << 4)));
        a = __builtin_amdgcn_mfma_f32_16x16x32_bf16(kf, qf[kc], a, 0, 0, 0);
      }
      st[mt] = a;
    }

    if (kt == ntiles - 1) {  // diagonal tile: mask key > q
      int qrow = wid * 16 + l15;
      #pragma unroll
      for (int mt = 0; mt < 4; ++mt)
        #pragma unroll
        for (int r = 0; r < 4; ++r)
          if (mt * 16 + g * 4 + r > qrow) st[mt][r] = -3.0e38f;
    }

    float tmax = -3.0e38f;
    #pragma unroll
    for (int mt = 0; mt < 4; ++mt)
      #pragma unroll
      for (int r = 0; r < 4; ++r) tmax = fmaxf(tmax, st[mt][r]);
    tmax = fmaxf(tmax, __shfl_xor(tmax, 16));
    tmax = fmaxf(tmax, __shfl_xor(tmax, 32));

    float m_new = fmaxf(m_run, tmax);
    float sc = exp2f(m_run - m_new);
    float psum = 0.f;
    u16 pb[16];
    #pragma unroll
    for (int mt = 0; mt < 4; ++mt)
      #pragma unroll
      for (int r = 0; r < 4; ++r) {
        float p = exp2f(st[mt][r] - m_new);
        psum += p;
        pb[mt * 4 + r] = f2bf(p);
      }
    psum += __shfl_xor(psum, 16);
    psum += __shfl_xor(psum, 32);
    l_run = l_run * sc + psum;
    m_run = m_new;
    #pragma unroll
    for (int mt = 0; mt < 4; ++mt)
      #pragma unroll
      for (int r = 0; r < 4; ++r) ot[mt][r] *= sc;

    // write P[q][key] (bf16) to this wave's LDS region
    char* Pw = Plds + wid * 2048;
    #pragma unroll
    for (int mt = 0; mt < 4; ++mt)
      #pragma unroll
      for (int r2 = 0; r2 < 2; ++r2) {
        u32 val = (u32)pb[mt * 4 + r2 * 2] | ((u32)pb[mt * 4 + r2 * 2 + 1] << 16);
        int cb = (mt * 32 + g * 8 + r2 * 4) ^ ((l15 & 7) << 4);
        *(u32*)(Pw + l15 * 128 + cb) = val;
      }
    asm volatile("s_waitcnt lgkmcnt(0)" ::: "memory");
    __builtin_amdgcn_sched_barrier(0);

    short8 pf[2];
    #pragma unroll
    for (int kc = 0; kc < 2; ++kc)
      pf[kc] = *(const short8*)(Pw + l15 * 128 + ((kc * 64 + g * 16) ^ ((l15 & 7) << 4)));

    // O^T += V^T @ P^T : rows = dv (mt*16 + 4g + r), cols = q (= l15)
    #pragma unroll
    for (int mt = 0; mt < 4; ++mt) {
      #pragma unroll
      for (int kc = 0; kc < 2; ++kc) {
        int dv = mt * 16 + l15;
        short8 vf = *(const short8*)(Vlds + dv * 128 + ((kc * 64 + g * 16) ^ ((dv & 7) << 4)));
        ot[mt] = __builtin_amdgcn_mfma_f32_16x16x32_bf16(vf, pf[kc], ot[mt], 0, 0, 0);
      }
    }
  }

  const float inv = 1.f / l_run;
  const int b = bh >> 4, h = bh & 15;
  const int t = wq0 + l15;
  u16* cp = CTX + ((size_t)(b * Tz + t)) * Dz + h * 64;
  #pragma unroll
  for (int mt = 0; mt < 4; ++mt)
    #pragma unroll
    for (int r = 0; r < 4; ++r)
      cp[mt * 16 + g * 4 + r] = f2bf(ot[mt][r] * inv);
}

extern "C" void kernel_launch(void* const* d_in, const int* in_sizes, int n_in,
                              void* d_out, int out_size, void* d_ws, size_t ws_size,
                              hipStream_t stream) {
  (void)in_sizes; (void)n_in; (void)out_size; (void)ws_size;
  const float* query = (const float*)d_in[0];
  const float* key   = (const float*)d_in[1];
  const float* value = (const float*)d_in[2];
  const float* Wq = (const float*)d_in[3];
  const float* bq = (const float*)d_in[4];
  const float* Wk = (const float*)d_in[5];
  const float* bk = (const float*)d_in[6];
  const float* Wv = (const float*)d_in[7];
  const float* bv = (const float*)d_in[8];
  const float* Wo = (const float*)d_in[9];
  const float* bo = (const float*)d_in[10];

  char* ws = (char*)d_ws;
  const size_t SZ_ACT = (size_t)Bz * Tz * Dz * sizeof(u16); // 16 MiB
  const size_t SZ_W = (size_t)Dz * Dz * sizeof(u16);        // 2 MiB
  u16* qw  = (u16*)(ws);
  u16* kw  = (u16*)(ws + SZ_ACT);
  u16* vw  = (u16*)(ws + 2 * SZ_ACT);
  u16* cw  = (u16*)(ws + 3 * SZ_ACT);
  u16* wqt = (u16*)(ws + 4 * SZ_ACT);
  u16* wkt = (u16*)(ws + 4 * SZ_ACT + SZ_W);
  u16* wvt = (u16*)(ws + 4 * SZ_ACT + 2 * SZ_W);
  u16* wot = (u16*)(ws + 4 * SZ_ACT + 3 * SZ_W);

  dim3 tg(32, 32);
  wt_kernel<<<tg, 256, 0, stream>>>(Wq, wqt);
  wt_kernel<<<tg, 256, 0, stream>>>(Wk, wkt);
  wt_kernel<<<tg, 256, 0, stream>>>(Wv, wvt);
  wt_kernel<<<tg, 256, 0, stream>>>(Wo, wot);

  dim3 gg(8, 64);  // x = N-blocks (share A panel in L2), y = M-blocks
  gemm_kernel<0, 0><<<gg, 256, 0, stream>>>(query, wqt, bq, qw, QSCALE);
  gemm_kernel<0, 0><<<gg, 256, 0, stream>>>(key,   wkt, bk, kw, 1.0f);
  gemm_kernel<0, 0><<<gg, 256, 0, stream>>>(value, wvt, bv, vw, 1.0f);

  attn_kernel<<<dim3(32, 64), 256, 0, stream>>>(qw, kw, vw, cw);

  gemm_kernel<1, 1><<<gg, 256, 0, stream>>>(cw, wot, bo, (float*)d_out, 1.0f);
}

// Round 2
// 295.031 us; speedup vs baseline: 1.4099x; 1.4099x over previous
//
#include <hip/hip_runtime.h>
#include <cstdint>

#define DEV static __device__ __forceinline__

typedef unsigned short u16;
typedef unsigned int u32;
using short8 = __attribute__((ext_vector_type(8))) short;
using f32x4  = __attribute__((ext_vector_type(4))) float;
using f32x16 = __attribute__((ext_vector_type(16))) float;
using u32x4  = __attribute__((ext_vector_type(4))) unsigned int;

constexpr int Bz = 4, Tz = 2048, Dz = 1024, Hz = 16;
// fold 1/sqrt(64) and log2(e) into Q so attention uses exp2 directly
constexpr float QSCALE = 0.125f * 1.4426950408889634f;

DEV u16 f2bf(float x) {
  union { float f; u32 u; } c; c.f = x;
  u32 u = c.u;
  return (u16)((u + 0x7FFFu + ((u >> 16) & 1u)) >> 16);
}

DEV u32 cvtpk(float a, float b) {
  u32 r;
  asm("v_cvt_pk_bf16_f32 %0, %1, %2" : "=v"(r) : "v"(a), "v"(b));
  return r;
}

// ---- weight transpose + convert: W (K x N fp32, K=N=1024) -> WT (N x K bf16)
__global__ void wt_kernel(const float* __restrict__ W, u16* __restrict__ WT) {
  __shared__ float tile[32][33];
  int n0 = blockIdx.x * 32, k0 = blockIdx.y * 32;
  int tx = threadIdx.x & 31, ty = threadIdx.x >> 5;
  #pragma unroll
  for (int i = 0; i < 32; i += 8)
    tile[ty + i][tx] = W[(size_t)(k0 + ty + i) * Dz + n0 + tx];
  __syncthreads();
  #pragma unroll
  for (int i = 0; i < 32; i += 8)
    WT[(size_t)(n0 + ty + i) * Dz + k0 + tx] = f2bf(tile[tx][ty + i]);
}

// ---- V transpose: (B,H,T,64) bf16 -> (B,H,64,T) bf16
__global__ __launch_bounds__(256) void vt_kernel(const u16* __restrict__ V,
                                                 u16* __restrict__ VT) {
  __shared__ char t[8192];   // [64 t][64 dv] bf16, 128B rows, XOR swizzled
  int bh = blockIdx.y, tt0 = blockIdx.x * 64;
  int tid = threadIdx.x;
  const char* src = (const char*)(V + ((size_t)bh * Tz + tt0) * 64);
  #pragma unroll
  for (int i = 0; i < 2; ++i) {
    int c = tid + i * 256;
    int row = c >> 3, colb = (c & 7) * 16;
    *(uint4*)(t + row * 128 + (colb ^ ((row & 7) << 4))) =
        *(const uint4*)(src + (size_t)row * 128 + colb);
  }
  __syncthreads();
  int dv = tid >> 2, ts = (tid & 3) * 16;
  u32 w[8];
  #pragma unroll
  for (int p = 0; p < 8; ++p) {
    int t1 = ts + 2 * p, t2 = t1 + 1;
    u32 lo = *(const u16*)(t + t1 * 128 + ((dv * 2) ^ ((t1 & 7) << 4)));
    u32 hi = *(const u16*)(t + t2 * 128 + ((dv * 2) ^ ((t2 & 7) << 4)));
    w[p] = lo | (hi << 16);
  }
  u16* dst = VT + ((size_t)bh * 64 + dv) * Tz + tt0 + ts;
  *(uint4*)(dst)     = uint4{w[0], w[1], w[2], w[3]};
  *(uint4*)(dst + 8) = uint4{w[4], w[5], w[6], w[7]};
}

// ---- GEMM: C[M=8192, N=1024] = A[M,1024] @ W[1024,N] (+bias)
// AMODE 0: A fp32 (converted to bf16 during staging); 1: A bf16
// EPI 0: scatter bf16 to (B,H,T,64) with (acc+bias)*scale ; 1: fp32 out + bias
template <int AMODE, int EPI>
__global__ __launch_bounds__(256) void gemm_kernel(
    const void* __restrict__ Aptr, const u16* __restrict__ WT,
    const float* __restrict__ bias, void* __restrict__ Cptr, float scale)
{
  __shared__ char lds[32 * 1024];
  char* Alds = lds;             // [128 rows][64 k] bf16, 128B rows, XOR-swizzled
  char* Blds = lds + 16 * 1024; // [128 n][64 k] bf16 (B^T), XOR-swizzled

  const int tid = threadIdx.x;
  const int lane = tid & 63, wid = tid >> 6;
  const int g = lane >> 4, l15 = lane & 15;
  const int n0 = blockIdx.x * 128, m0 = blockIdx.y * 128;
  const int wm = (wid >> 1) * 64, wn = (wid & 1) * 64;

  f32x4 acc[4][4] = {};

  for (int k0 = 0; k0 < Dz; k0 += 64) {
    if (AMODE == 0) {
      const float* A = (const float*)Aptr;
      #pragma unroll
      for (int i = 0; i < 8; ++i) {
        int c = tid + i * 256;              // 2048 chunks of 4 floats
        int row = c >> 4, f0 = (c & 15) * 4;
        float4 v = *(const float4*)(A + (size_t)(m0 + row) * Dz + k0 + f0);
        u32 lo = (u32)f2bf(v.x) | ((u32)f2bf(v.y) << 16);
        u32 hi = (u32)f2bf(v.z) | ((u32)f2bf(v.w) << 16);
        int off = row * 128 + ((f0 * 2) ^ ((row & 7) << 4));
        *(uint2*)(Alds + off) = make_uint2(lo, hi);
      }
    } else {
      const u16* A = (const u16*)Aptr;
      #pragma unroll
      for (int i = 0; i < 4; ++i) {
        int c = tid + i * 256;              // 1024 chunks of 16B
        int row = c >> 3, cb = (c & 7) * 16;
        uint4 v = *(const uint4*)(A + (size_t)(m0 + row) * Dz + k0 + (cb >> 1));
        *(uint4*)(Alds + row * 128 + (cb ^ ((row & 7) << 4))) = v;
      }
    }
    #pragma unroll
    for (int i = 0; i < 4; ++i) {
      int c = tid + i * 256;
      int row = c >> 3, cb = (c & 7) * 16;
      uint4 v = *(const uint4*)(WT + (size_t)(n0 + row) * Dz + k0 + (cb >> 1));
      *(uint4*)(Blds + row * 128 + (cb ^ ((row & 7) << 4))) = v;
    }
    __syncthreads();

    #pragma unroll
    for (int kc = 0; kc < 2; ++kc) {
      short8 af[4], bfv[4];
      #pragma unroll
      for (int mt = 0; mt < 4; ++mt) {
        int row = wm + mt * 16 + l15;
        af[mt] = *(const short8*)(Alds + row * 128 + ((kc * 64 + g * 16) ^ ((row & 7) << 4)));
      }
      #pragma unroll
      for (int nt = 0; nt < 4; ++nt) {
        int row = wn + nt * 16 + l15;
        bfv[nt] = *(const short8*)(Blds + row * 128 + ((kc * 64 + g * 16) ^ ((row & 7) << 4)));
      }
      #pragma unroll
      for (int mt = 0; mt < 4; ++mt)
        #pragma unroll
        for (int nt = 0; nt < 4; ++nt)
          acc[mt][nt] = __builtin_amdgcn_mfma_f32_16x16x32_bf16(af[mt], bfv[nt], acc[mt][nt], 0, 0, 0);
    }
    __syncthreads();
  }

  if (EPI == 0) {
    u16* C = (u16*)Cptr;
    #pragma unroll
    for (int nt = 0; nt < 4; ++nt) {
      int n = n0 + wn + nt * 16 + l15;
      float bv = bias[n];
      int h = n >> 6, dh = n & 63;
      #pragma unroll
      for (int mt = 0; mt < 4; ++mt)
        #pragma unroll
        for (int r = 0; r < 4; ++r) {
          int m = m0 + wm + mt * 16 + g * 4 + r;
          int bb = m >> 11, t = m & 2047;
          float val = (acc[mt][nt][r] + bv) * scale;
          C[((size_t)(bb * Hz + h) * Tz + t) * 64 + dh] = f2bf(val);
        }
    }
  } else {
    float* C = (float*)Cptr;
    #pragma unroll
    for (int nt = 0; nt < 4; ++nt) {
      int n = n0 + wn + nt * 16 + l15;
      float bv = bias[n];
      #pragma unroll
      for (int mt = 0; mt < 4; ++mt)
        #pragma unroll
        for (int r = 0; r < 4; ++r) {
          int m = m0 + wm + mt * 16 + g * 4 + r;
          C[(size_t)m * Dz + n] = acc[mt][nt][r] + bv;
        }
    }
  }
}

// P fragment builder: 8 f32 P-values (regs base..base+7 of one 32-key S^T tile)
// -> bf16 B-fragment (16 keys) via cvt_pk + permlane32_swap (T12 mapping):
//   word0,word2 = swap(pk(p0,p1), pk(p4,p5)); word1,word3 = swap(pk(p2,p3), pk(p6,p7))
DEV short8 mk_pb(float p0, float p1, float p2, float p3,
                 float p4, float p5, float p6, float p7) {
  u32 x0 = cvtpk(p0, p1), y0 = cvtpk(p4, p5);
  u32 x1 = cvtpk(p2, p3), y1 = cvtpk(p6, p7);
  asm("v_permlane32_swap_b32 %0, %1" : "+v"(x0), "+v"(y0));
  asm("v_permlane32_swap_b32 %0, %1" : "+v"(x1), "+v"(y1));
  u32x4 w = {x0, x1, y0, y1};
  return __builtin_bit_cast(short8, w);
}

// ---- flash attention: q,k in (B,H,T,64) bf16 (q pre-scaled by 0.125*log2e),
// vt in (B,H,64,T) bf16. 4 waves x 32 q-rows, KVBLK=64, 32x32x16 MFMAs.
//   S^T = mfma(K, Q): col = q = lane&31 (lane-local softmax rows)
//   O^T = mfma(V^T, P^T): col = q -> shuffle-free rescale; P built in-register.
__global__ __launch_bounds__(256) void attn_kernel(
    const u16* __restrict__ Q, const u16* __restrict__ K,
    const u16* __restrict__ VT, u16* __restrict__ CTX)
{
  __shared__ char lds[16384];
  char* Klds = lds;         // [64 key][64 dk] bf16, swizzled ^((key&7)<<4)
  char* Vlds = lds + 8192;  // [64 dv][64 key] bf16, swizzled ^((dv&7)<<4)

  const int tid = threadIdx.x;
  const int lane = tid & 63, wid = tid >> 6;
  const int l31 = lane & 31, hi = lane >> 5;
  const int t0 = (15 - blockIdx.x) * 128;   // reversed: longest blocks first
  const int bh = blockIdx.y;

  const u16* qb  = Q  + (size_t)bh * Tz * 64;
  const u16* kb  = K  + (size_t)bh * Tz * 64;
  const u16* vtb = VT + (size_t)bh * 64 * Tz;

  const int wq0 = t0 + wid * 32;
  const int qg  = wq0 + l31;
  const int wqhi = wq0 + 31;

  short8 qf[4];
  #pragma unroll
  for (int kc = 0; kc < 4; ++kc)
    qf[kc] = *(const short8*)(qb + (size_t)qg * 64 + kc * 16 + hi * 8);

  f32x16 o0 = {}, o1 = {};
  float m_run = -3.0e38f, l_run = 0.f;

  const int ntiles = t0 / 64 + 2;
  for (int kt = 0; kt < ntiles; ++kt) {
    const int kv0 = kt * 64;
    __syncthreads();
    #pragma unroll
    for (int i = 0; i < 2; ++i) {
      int c = tid + i * 256;
      int row = c >> 3, colb = (c & 7) * 16;
      int sw = colb ^ ((row & 7) << 4);
      *(uint4*)(Klds + row * 128 + sw) =
          *(const uint4*)((const char*)kb + (size_t)(kv0 + row) * 128 + colb);
      *(uint4*)(Vlds + row * 128 + sw) =
          *(const uint4*)((const char*)vtb + (size_t)row * (Tz * 2) + (size_t)kv0 * 2 + colb);
    }
    __syncthreads();

    if (kv0 > wqhi) continue;   // fully masked for this wave (barriers stay uniform)

    // ---- S^T = K @ Q^T : rows = keys, cols = q
    f32x16 s0 = {}, s1 = {};
    const int swz = (l31 & 7) << 4;
    #pragma unroll
    for (int kc = 0; kc < 4; ++kc) {
      int cb = (kc * 32 + hi * 16) ^ swz;
      short8 kf0 = *(const short8*)(Klds + l31 * 128 + cb);
      short8 kf1 = *(const short8*)(Klds + (32 + l31) * 128 + cb);
      s0 = __builtin_amdgcn_mfma_f32_32x32x16_bf16(kf0, qf[kc], s0, 0, 0, 0);
      s1 = __builtin_amdgcn_mfma_f32_32x32x16_bf16(kf1, qf[kc], s1, 0, 0, 0);
    }

    if (kv0 + 63 > wq0) {       // diagonal: mask key > q
      #pragma unroll
      for (int r = 0; r < 16; ++r) {
        int kg = kv0 + (r & 3) + 8 * (r >> 2) + 4 * hi;
        if (kg > qg)      s0[r] = -3.0e38f;
        if (kg + 32 > qg) s1[r] = -3.0e38f;
      }
    }

    // ---- online softmax (q is lane-local; partner lane^32 holds other 32 keys)
    float tmax = fmaxf(s0[0], s1[0]);
    #pragma unroll
    for (int r = 1; r < 16; ++r) tmax = fmaxf(tmax, fmaxf(s0[r], s1[r]));
    tmax = fmaxf(tmax, __shfl_xor(tmax, 32));
    float m_new = fmaxf(m_run, tmax);
    float sc = __builtin_amdgcn_exp2f(m_run - m_new);
    float psum = 0.f;
    #pragma unroll
    for (int r = 0; r < 16; ++r) {
      s0[r] = __builtin_amdgcn_exp2f(s0[r] - m_new); psum += s0[r];
      s1[r] = __builtin_amdgcn_exp2f(s1[r] - m_new); psum += s1[r];
    }
    psum += __shfl_xor(psum, 32);
    l_run = l_run * sc + psum;
    m_run = m_new;
    #pragma unroll
    for (int r = 0; r < 16; ++r) { o0[r] *= sc; o1[r] *= sc; }

    // ---- P -> bf16 B-fragments (in-register, no LDS)
    short8 pb0 = mk_pb(s0[0], s0[1], s0[2],  s0[3],  s0[4],  s0[5],  s0[6],  s0[7]);
    short8 pb1 = mk_pb(s0[8], s0[9], s0[10], s0[11], s0[12], s0[13], s0[14], s0[15]);
    short8 pb2 = mk_pb(s1[0], s1[1], s1[2],  s1[3],  s1[4],  s1[5],  s1[6],  s1[7]);
    short8 pb3 = mk_pb(s1[8], s1[9], s1[10], s1[11], s1[12], s1[13], s1[14], s1[15]);

    // ---- O^T += V^T @ P^T : rows = dv, cols = q
    #pragma unroll
    for (int kc = 0; kc < 4; ++kc) {
      int cb = (kc * 32 + hi * 16) ^ swz;
      short8 vf0 = *(const short8*)(Vlds + l31 * 128 + cb);
      short8 vf1 = *(const short8*)(Vlds + (32 + l31) * 128 + cb);
      short8 pbk = (kc == 0) ? pb0 : (kc == 1) ? pb1 : (kc == 2) ? pb2 : pb3;
      o0 = __builtin_amdgcn_mfma_f32_32x32x16_bf16(vf0, pbk, o0, 0, 0, 0);
      o1 = __builtin_amdgcn_mfma_f32_32x32x16_bf16(vf1, pbk, o1, 0, 0, 0);
    }
  }

  // ---- epilogue: O[q][dv] / l -> ctx (B*T, H*64) bf16
  const float linv = 1.0f / l_run;
  const int b = bh >> 4, h = bh & 15;
  u16* cp = CTX + ((size_t)(b * Tz + qg)) * Dz + h * 64;
  #pragma unroll
  for (int rq = 0; rq < 4; ++rq) {
    int dv0 = 8 * rq + 4 * hi;
    u32 w0 = cvtpk(o0[rq * 4 + 0] * linv, o0[rq * 4 + 1] * linv);
    u32 w1 = cvtpk(o0[rq * 4 + 2] * linv, o0[rq * 4 + 3] * linv);
    *(uint2*)(cp + dv0) = make_uint2(w0, w1);
    u32 w2 = cvtpk(o1[rq * 4 + 0] * linv, o1[rq * 4 + 1] * linv);
    u32 w3 = cvtpk(o1[rq * 4 + 2] * linv, o1[rq * 4 + 3] * linv);
    *(uint2*)(cp + 32 + dv0) = make_uint2(w2, w3);
  }
}

extern "C" void kernel_launch(void* const* d_in, const int* in_sizes, int n_in,
                              void* d_out, int out_size, void* d_ws, size_t ws_size,
                              hipStream_t stream) {
  (void)in_sizes; (void)n_in; (void)out_size; (void)ws_size;
  const float* query = (const float*)d_in[0];
  const float* key   = (const float*)d_in[1];
  const float* value = (const float*)d_in[2];
  const float* Wq = (const float*)d_in[3];
  const float* bq = (const float*)d_in[4];
  const float* Wk = (const float*)d_in[5];
  const float* bk = (const float*)d_in[6];
  const float* Wv = (const float*)d_in[7];
  const float* bv = (const float*)d_in[8];
  const float* Wo = (const float*)d_in[9];
  const float* bo = (const float*)d_in[10];

  char* ws = (char*)d_ws;
  const size_t SZ_ACT = (size_t)Bz * Tz * Dz * sizeof(u16); // 16 MiB
  const size_t SZ_W = (size_t)Dz * Dz * sizeof(u16);        // 2 MiB
  u16* qw  = (u16*)(ws);
  u16* kw  = (u16*)(ws + SZ_ACT);
  u16* vw  = (u16*)(ws + 2 * SZ_ACT);
  u16* vtw = (u16*)(ws + 3 * SZ_ACT);
  u16* cw  = vw;  // attn output reuses vw (attn reads vtw, not vw)
  u16* wqt = (u16*)(ws + 4 * SZ_ACT);
  u16* wkt = (u16*)(ws + 4 * SZ_ACT + SZ_W);
  u16* wvt = (u16*)(ws + 4 * SZ_ACT + 2 * SZ_W);
  u16* wot = (u16*)(ws + 4 * SZ_ACT + 3 * SZ_W);

  dim3 tg(32, 32);
  wt_kernel<<<tg, 256, 0, stream>>>(Wq, wqt);
  wt_kernel<<<tg, 256, 0, stream>>>(Wk, wkt);
  wt_kernel<<<tg, 256, 0, stream>>>(Wv, wvt);
  wt_kernel<<<tg, 256, 0, stream>>>(Wo, wot);

  dim3 gg(8, 64);  // x = N-blocks (share A panel in L2), y = M-blocks
  gemm_kernel<0, 0><<<gg, 256, 0, stream>>>(query, wqt, bq, qw, QSCALE);
  gemm_kernel<0, 0><<<gg, 256, 0, stream>>>(key,   wkt, bk, kw, 1.0f);
  gemm_kernel<0, 0><<<gg, 256, 0, stream>>>(value, wvt, bv, vw, 1.0f);

  vt_kernel<<<dim3(Tz / 64, Bz * Hz), 256, 0, stream>>>(vw, vtw);

  attn_kernel<<<dim3(16, Bz * Hz), 256, 0, stream>>>(qw, kw, vtw, cw);

  gemm_kernel<1, 1><<<gg, 256, 0, stream>>>(cw, wot, bo, (float*)d_out, 1.0f);
}

// Round 3
// 221.143 us; speedup vs baseline: 1.8810x; 1.3341x over previous
//
#include <hip/hip_runtime.h>
#include <cstdint>

#define DEV static __device__ __forceinline__

typedef unsigned short u16;
typedef unsigned int u32;
using short8 = __attribute__((ext_vector_type(8))) short;
using f32x4  = __attribute__((ext_vector_type(4))) float;
using f32x16 = __attribute__((ext_vector_type(16))) float;
using u32x4  = __attribute__((ext_vector_type(4))) unsigned int;

constexpr int Bz = 4, Tz = 2048, Dz = 1024, Hz = 16;
// fold 1/sqrt(64) and log2(e) into Q so attention uses exp2 directly
constexpr float QSCALE = 0.125f * 1.4426950408889634f;

DEV u16 f2bf(float x) {
  union { float f; u32 u; } c; c.f = x;
  u32 u = c.u;
  return (u16)((u + 0x7FFFu + ((u >> 16) & 1u)) >> 16);
}

DEV u32 cvtpk(float a, float b) {
  u32 r;
  asm("v_cvt_pk_bf16_f32 %0, %1, %2" : "=v"(r) : "v"(a), "v"(b));
  return r;
}

// async global->LDS DMA, 16B per lane. LDS dest must be linear in lane order.
DEV void gload16(const void* g, void* l) {
  __builtin_amdgcn_global_load_lds(
      (const __attribute__((address_space(1))) void*)g,
      (__attribute__((address_space(3))) void*)l, 16, 0, 0);
}

// ---- fp32 -> bf16 elementwise convert (8 elems/thread)
__global__ __launch_bounds__(256) void cvt_kernel(const float* __restrict__ X,
                                                  u16* __restrict__ Y) {
  int i = blockIdx.x * 256 + threadIdx.x;
  float4 a = ((const float4*)X)[i * 2];
  float4 b = ((const float4*)X)[i * 2 + 1];
  uint4 o;
  o.x = cvtpk(a.x, a.y); o.y = cvtpk(a.z, a.w);
  o.z = cvtpk(b.x, b.y); o.w = cvtpk(b.z, b.w);
  ((uint4*)Y)[i] = o;
}

// ---- weight transpose + convert: W (K x N fp32, K=N=1024) -> WT (N x K bf16)
__global__ void wt_kernel(const float* __restrict__ W, u16* __restrict__ WT) {
  __shared__ float tile[32][33];
  int n0 = blockIdx.x * 32, k0 = blockIdx.y * 32;
  int tx = threadIdx.x & 31, ty = threadIdx.x >> 5;
  #pragma unroll
  for (int i = 0; i < 32; i += 8)
    tile[ty + i][tx] = W[(size_t)(k0 + ty + i) * Dz + n0 + tx];
  __syncthreads();
  #pragma unroll
  for (int i = 0; i < 32; i += 8)
    WT[(size_t)(n0 + ty + i) * Dz + k0 + tx] = f2bf(tile[tx][ty + i]);
}

// ---- V transpose: (B,H,T,64) bf16 -> (B,H,64,T) bf16
__global__ __launch_bounds__(256) void vt_kernel(const u16* __restrict__ V,
                                                 u16* __restrict__ VT) {
  __shared__ char t[8192];   // [64 t][64 dv] bf16, 128B rows, XOR swizzled
  int bh = blockIdx.y, tt0 = blockIdx.x * 64;
  int tid = threadIdx.x;
  const char* src = (const char*)(V + ((size_t)bh * Tz + tt0) * 64);
  #pragma unroll
  for (int i = 0; i < 2; ++i) {
    int c = tid + i * 256;
    int row = c >> 3, colb = (c & 7) * 16;
    *(uint4*)(t + row * 128 + (colb ^ ((row & 7) << 4))) =
        *(const uint4*)(src + (size_t)row * 128 + colb);
  }
  __syncthreads();
  int dv = tid >> 2, ts = (tid & 3) * 16;
  u32 w[8];
  #pragma unroll
  for (int p = 0; p < 8; ++p) {
    int t1 = ts + 2 * p, t2 = t1 + 1;
    u32 lo = *(const u16*)(t + t1 * 128 + ((dv * 2) ^ ((t1 & 7) << 4)));
    u32 hi = *(const u16*)(t + t2 * 128 + ((dv * 2) ^ ((t2 & 7) << 4)));
    w[p] = lo | (hi << 16);
  }
  u16* dst = VT + ((size_t)bh * 64 + dv) * Tz + tt0 + ts;
  *(uint4*)(dst)     = uint4{w[0], w[1], w[2], w[3]};
  *(uint4*)(dst + 8) = uint4{w[4], w[5], w[6], w[7]};
}

// ---- GEMM: C[M=8192, N=1024] = A[M,1024]bf16 @ W[1024,N] (+bias)
// m97-structure: global_load_lds both operands, linear LDS, T3 2-phase dbuf.
// EPI 0: scatter bf16 to (B,H,T,64) with (acc+bias)*scale ; 1: fp32 out + bias
template <int EPI>
__global__ __launch_bounds__(256) void gemm_kernel(
    const u16* __restrict__ A, const u16* __restrict__ WT,
    const float* __restrict__ bias, void* __restrict__ Cptr, float scale)
{
  __shared__ u16 lds[2][16384];  // [dbuf][A 128x64 | B 128x64]

  const int tid = threadIdx.x;
  const int lane = tid & 63, wid = tid >> 6;
  const int g = lane >> 4, l15 = lane & 15;
  const int n0 = blockIdx.x * 128, m0 = blockIdx.y * 128;
  const int wm = (wid >> 1) * 64, wn = (wid & 1) * 64;

  f32x4 acc[4][4] = {};

  auto stage = [&](int buf, int k0) {
    #pragma unroll
    for (int i = 0; i < 4; ++i) {
      int c = tid + i * 256;             // 1024 chunks of 16B per tensor
      int row = c >> 3, cb8 = (c & 7) * 8;
      gload16(A  + (size_t)(m0 + row) * Dz + k0 + cb8, &lds[buf][c * 8]);
      gload16(WT + (size_t)(n0 + row) * Dz + k0 + cb8, &lds[buf][8192 + c * 8]);
    }
  };

  stage(0, 0);
  __syncthreads();   // drains vmcnt (compiler emits full waitcnt before barrier)

  int cur = 0;
  for (int step = 0; step < 16; ++step) {
    if (step < 15) stage(cur ^ 1, (step + 1) * 64);
    const u16* Ab = &lds[cur][0];
    const u16* Bb = &lds[cur][8192];
    #pragma unroll
    for (int kc = 0; kc < 2; ++kc) {
      short8 af[4], bfv[4];
      #pragma unroll
      for (int mt = 0; mt < 4; ++mt)
        af[mt] = *(const short8*)(Ab + (wm + mt * 16 + l15) * 64 + kc * 32 + g * 8);
      #pragma unroll
      for (int nt = 0; nt < 4; ++nt)
        bfv[nt] = *(const short8*)(Bb + (wn + nt * 16 + l15) * 64 + kc * 32 + g * 8);
      #pragma unroll
      for (int mt = 0; mt < 4; ++mt)
        #pragma unroll
        for (int nt = 0; nt < 4; ++nt)
          acc[mt][nt] = __builtin_amdgcn_mfma_f32_16x16x32_bf16(af[mt], bfv[nt], acc[mt][nt], 0, 0, 0);
    }
    __syncthreads();
    cur ^= 1;
  }

  if (EPI == 0) {
    u16* C = (u16*)Cptr;
    #pragma unroll
    for (int nt = 0; nt < 4; ++nt) {
      int n = n0 + wn + nt * 16 + l15;
      float bv = bias[n];
      int h = n >> 6, dh = n & 63;
      #pragma unroll
      for (int mt = 0; mt < 4; ++mt)
        #pragma unroll
        for (int r = 0; r < 4; ++r) {
          int m = m0 + wm + mt * 16 + g * 4 + r;
          int bb = m >> 11, t = m & 2047;
          float val = (acc[mt][nt][r] + bv) * scale;
          C[((size_t)(bb * Hz + h) * Tz + t) * 64 + dh] = f2bf(val);
        }
    }
  } else {
    float* C = (float*)Cptr;
    #pragma unroll
    for (int nt = 0; nt < 4; ++nt) {
      int n = n0 + wn + nt * 16 + l15;
      float bv = bias[n];
      #pragma unroll
      for (int mt = 0; mt < 4; ++mt)
        #pragma unroll
        for (int r = 0; r < 4; ++r) {
          int m = m0 + wm + mt * 16 + g * 4 + r;
          C[(size_t)m * Dz + n] = acc[mt][nt][r] + bv;
        }
    }
  }
}

// P fragment builder (T12): 8 f32 P-values -> bf16 B-fragment (16 keys)
DEV short8 mk_pb(float p0, float p1, float p2, float p3,
                 float p4, float p5, float p6, float p7) {
  u32 x0 = cvtpk(p0, p1), y0 = cvtpk(p4, p5);
  u32 x1 = cvtpk(p2, p3), y1 = cvtpk(p6, p7);
  asm("v_permlane32_swap_b32 %0, %1" : "+v"(x0), "+v"(y0));
  asm("v_permlane32_swap_b32 %0, %1" : "+v"(x1), "+v"(y1));
  u32x4 w = {x0, x1, y0, y1};
  return __builtin_bit_cast(short8, w);
}

// ---- flash attention: q,k in (B,H,T,64) bf16 (q pre-scaled), vt in (B,H,64,T).
// Pair-balanced: block handles q-tiles j and 15-j (uniform 34 KV-tile visits).
// T3 dbuf: gload_lds staging with pre-swizzled source, one barrier per tile.
__global__ __launch_bounds__(256) void attn_kernel(
    const u16* __restrict__ Q, const u16* __restrict__ K,
    const u16* __restrict__ VT, u16* __restrict__ CTX)
{
  __shared__ char lds[32768];  // [2 dbuf][K 8KB | VT 8KB]

  const int tid = threadIdx.x;
  const int lane = tid & 63, wid = tid >> 6;
  const int l31 = lane & 31, hi = lane >> 5;
  const int pr = blockIdx.x;      // 0..7
  const int bh = blockIdx.y;
  const int b = bh >> 4, h = bh & 15;

  const u16* qb  = Q  + (size_t)bh * Tz * 64;
  const u16* kb  = K  + (size_t)bh * Tz * 64;
  const u16* vtb = VT + (size_t)bh * 64 * Tz;

  auto stage = [&](int buf, int kv0) {
    char* Kl = lds + buf * 16384;
    char* Vl = Kl + 8192;
    #pragma unroll
    for (int i = 0; i < 2; ++i) {
      int c = tid + i * 256;            // 512 chunks of 16B per tensor
      int row = c >> 3, colb = (c & 7) * 16;
      int cbs = colb ^ ((row & 7) << 4);   // pre-swizzled source column
      gload16(kb  + (size_t)(kv0 + row) * 64 + (cbs >> 1), Kl + c * 16);
      gload16(vtb + (size_t)row * Tz + kv0 + (cbs >> 1),  Vl + c * 16);
    }
  };

  #pragma unroll 1
  for (int half = 0; half < 2; ++half) {
    const int j = half ? (15 - pr) : pr;
    const int t0 = j * 128;
    const int ntiles = 2 * j + 2;
    const int wq0 = t0 + wid * 32;
    const int qg = wq0 + l31, wqhi = wq0 + 31;

    stage(0, 0);

    short8 qf[4];
    #pragma unroll
    for (int kc = 0; kc < 4; ++kc)
      qf[kc] = *(const short8*)(qb + (size_t)qg * 64 + kc * 16 + hi * 8);

    f32x16 o0 = {}, o1 = {};
    float m_run = -3.0e38f, l_run = 0.f;

    __syncthreads();   // drain stage(0)

    int cur = 0;
    for (int kt = 0; kt < ntiles; ++kt) {
      const int kv0 = kt * 64;
      if (kt + 1 < ntiles) stage(cur ^ 1, (kt + 1) * 64);

      if (kv0 <= wqhi) {
        const char* Kl = lds + cur * 16384;
        const char* Vl = Kl + 8192;
        const int swz = (l31 & 7) << 4;

        // ---- S^T = K @ Q^T : rows = keys, cols = q
        f32x16 s0 = {}, s1 = {};
        #pragma unroll
        for (int kc = 0; kc < 4; ++kc) {
          int cb = (kc * 32 + hi * 16) ^ swz;
          short8 kf0 = *(const short8*)(Kl + l31 * 128 + cb);
          short8 kf1 = *(const short8*)(Kl + (32 + l31) * 128 + cb);
          s0 = __builtin_amdgcn_mfma_f32_32x32x16_bf16(kf0, qf[kc], s0, 0, 0, 0);
          s1 = __builtin_amdgcn_mfma_f32_32x32x16_bf16(kf1, qf[kc], s1, 0, 0, 0);
        }

        if (kv0 + 63 > wq0) {       // diagonal: mask key > q
          #pragma unroll
          for (int r = 0; r < 16; ++r) {
            int kg = kv0 + (r & 3) + 8 * (r >> 2) + 4 * hi;
            if (kg > qg)      s0[r] = -3.0e38f;
            if (kg + 32 > qg) s1[r] = -3.0e38f;
          }
        }

        // ---- online softmax with defer-max (T13, THR=8)
        float tmax = fmaxf(s0[0], s1[0]);
        #pragma unroll
        for (int r = 1; r < 16; ++r) tmax = fmaxf(tmax, fmaxf(s0[r], s1[r]));
        tmax = fmaxf(tmax, __shfl_xor(tmax, 32));

        if (__any(tmax > m_run + 8.f)) {
          float m_new = fmaxf(m_run, tmax);
          float sc = __builtin_amdgcn_exp2f(m_run - m_new);
          l_run *= sc;
          #pragma unroll
          for (int r = 0; r < 16; ++r) { o0[r] *= sc; o1[r] *= sc; }
          m_run = m_new;
        }
        float psum = 0.f;
        #pragma unroll
        for (int r = 0; r < 16; ++r) {
          s0[r] = __builtin_amdgcn_exp2f(s0[r] - m_run); psum += s0[r];
          s1[r] = __builtin_amdgcn_exp2f(s1[r] - m_run); psum += s1[r];
        }
        psum += __shfl_xor(psum, 32);
        l_run += psum;

        // ---- P -> bf16 B-fragments (in-register)
        short8 pb0 = mk_pb(s0[0], s0[1], s0[2],  s0[3],  s0[4],  s0[5],  s0[6],  s0[7]);
        short8 pb1 = mk_pb(s0[8], s0[9], s0[10], s0[11], s0[12], s0[13], s0[14], s0[15]);
        short8 pb2 = mk_pb(s1[0], s1[1], s1[2],  s1[3],  s1[4],  s1[5],  s1[6],  s1[7]);
        short8 pb3 = mk_pb(s1[8], s1[9], s1[10], s1[11], s1[12], s1[13], s1[14], s1[15]);

        // ---- O^T += V^T @ P^T : rows = dv, cols = q
        #pragma unroll
        for (int kc = 0; kc < 4; ++kc) {
          int cb = (kc * 32 + hi * 16) ^ swz;
          short8 vf0 = *(const short8*)(Vl + l31 * 128 + cb);
          short8 vf1 = *(const short8*)(Vl + (32 + l31) * 128 + cb);
          short8 pbk = (kc == 0) ? pb0 : (kc == 1) ? pb1 : (kc == 2) ? pb2 : pb3;
          o0 = __builtin_amdgcn_mfma_f32_32x32x16_bf16(vf0, pbk, o0, 0, 0, 0);
          o1 = __builtin_amdgcn_mfma_f32_32x32x16_bf16(vf1, pbk, o1, 0, 0, 0);
        }
      }

      __syncthreads();   // drains stage(kt+1) DMA; separates buffer reuse
      cur ^= 1;
    }

    // ---- epilogue: O[q][dv] / l -> ctx (B*T, H*64) bf16
    const float linv = 1.0f / l_run;
    u16* cp = CTX + ((size_t)(b * Tz + qg)) * Dz + h * 64;
    #pragma unroll
    for (int rq = 0; rq < 4; ++rq) {
      int dv0 = 8 * rq + 4 * hi;
      u32 w0 = cvtpk(o0[rq * 4 + 0] * linv, o0[rq * 4 + 1] * linv);
      u32 w1 = cvtpk(o0[rq * 4 + 2] * linv, o0[rq * 4 + 3] * linv);
      *(uint2*)(cp + dv0) = make_uint2(w0, w1);
      u32 w2 = cvtpk(o1[rq * 4 + 0] * linv, o1[rq * 4 + 1] * linv);
      u32 w3 = cvtpk(o1[rq * 4 + 2] * linv, o1[rq * 4 + 3] * linv);
      *(uint2*)(cp + 32 + dv0) = make_uint2(w2, w3);
    }
  }
}

extern "C" void kernel_launch(void* const* d_in, const int* in_sizes, int n_in,
                              void* d_out, int out_size, void* d_ws, size_t ws_size,
                              hipStream_t stream) {
  (void)in_sizes; (void)n_in; (void)out_size; (void)ws_size;
  const float* query = (const float*)d_in[0];
  const float* key   = (const float*)d_in[1];
  const float* value = (const float*)d_in[2];
  const float* Wq = (const float*)d_in[3];
  const float* bq = (const float*)d_in[4];
  const float* Wk = (const float*)d_in[5];
  const float* bk = (const float*)d_in[6];
  const float* Wv = (const float*)d_in[7];
  const float* bv = (const float*)d_in[8];
  const float* Wo = (const float*)d_in[9];
  const float* bo = (const float*)d_in[10];

  char* ws = (char*)d_ws;
  const size_t SZ_ACT = (size_t)Bz * Tz * Dz * sizeof(u16); // 16 MiB
  const size_t SZ_W = (size_t)Dz * Dz * sizeof(u16);        // 2 MiB
  u16* qw  = (u16*)(ws);
  u16* kw  = (u16*)(ws + SZ_ACT);
  u16* vw  = (u16*)(ws + 2 * SZ_ACT);
  u16* qx  = (u16*)(ws + 3 * SZ_ACT);  // bf16 query; later reused as vtw
  u16* vtw = qx;                       // alias: qx dead after q-GEMM
  u16* cw  = vw;                       // attn output reuses vw (attn reads vtw)
  u16* wqt = (u16*)(ws + 4 * SZ_ACT);
  u16* wkt = (u16*)(ws + 4 * SZ_ACT + SZ_W);
  u16* wvt = (u16*)(ws + 4 * SZ_ACT + 2 * SZ_W);
  u16* wot = (u16*)(ws + 4 * SZ_ACT + 3 * SZ_W);
  // kx/vx live in d_out (32 MiB): dead before the final GEMM writes d_out
  u16* kx = (u16*)d_out;
  u16* vx = (u16*)d_out + (size_t)Bz * Tz * Dz;

  const int CVTG = (Bz * Tz * Dz) / (256 * 8);
  cvt_kernel<<<CVTG, 256, 0, stream>>>(query, qx);
  cvt_kernel<<<CVTG, 256, 0, stream>>>(key,   kx);
  cvt_kernel<<<CVTG, 256, 0, stream>>>(value, vx);

  dim3 tg(32, 32);
  wt_kernel<<<tg, 256, 0, stream>>>(Wq, wqt);
  wt_kernel<<<tg, 256, 0, stream>>>(Wk, wkt);
  wt_kernel<<<tg, 256, 0, stream>>>(Wv, wvt);
  wt_kernel<<<tg, 256, 0, stream>>>(Wo, wot);

  dim3 gg(8, 64);  // x = N-blocks (share A panel in L2), y = M-blocks
  gemm_kernel<0><<<gg, 256, 0, stream>>>(qx, wqt, bq, qw, QSCALE);
  gemm_kernel<0><<<gg, 256, 0, stream>>>(kx, wkt, bk, kw, 1.0f);
  gemm_kernel<0><<<gg, 256, 0, stream>>>(vx, wvt, bv, vw, 1.0f);

  vt_kernel<<<dim3(Tz / 64, Bz * Hz), 256, 0, stream>>>(vw, vtw);

  attn_kernel<<<dim3(8, Bz * Hz), 256, 0, stream>>>(qw, kw, vtw, cw);

  gemm_kernel<1><<<gg, 256, 0, stream>>>(cw, wot, bo, (float*)d_out, 1.0f);
}